// Round 1
// baseline (2257.983 us; speedup 1.0000x reference)
//
#include <hip/hip_runtime.h>

#define N_NODES 50000
#define N_EDGES 800000
// IN=128, HID=128, OUT=64

// ---------------- workspace layout (float elements) ----------------
// deg  : [50000]           @ 0
// agg1 : [50000*128]       @ 50048
// h1   : [50000*128]       @ 6450048
// p2   : [50000*64]        @ 12850048
// agg2 : [50000*64]        @ 16050048
#define OFF_DEG   0
#define OFF_AGG1  50048
#define OFF_H1    6450048
#define OFF_P2    12850048
#define OFF_AGG2  16050048

__global__ __launch_bounds__(256) void deg_kernel(const int* __restrict__ dst,
                                                  float* __restrict__ deg) {
    int e = blockIdx.x * 256 + threadIdx.x;
    if (e < N_EDGES) atomicAdd(&deg[dst[e]], 1.0f);
}

// one edge handled by 32 threads, 4 floats each (128 features)
__global__ __launch_bounds__(256) void scatter128_kernel(const int* __restrict__ src,
                                                         const int* __restrict__ dst,
                                                         const float* __restrict__ x,
                                                         float* __restrict__ agg) {
    unsigned tid = blockIdx.x * 256u + threadIdx.x;
    unsigned e = tid >> 5;
    unsigned t = tid & 31;
    if (e >= N_EDGES) return;
    int s = src[e], d = dst[e];
    float4 v = *(const float4*)(x + (long)s * 128 + t * 4);
    float* a = agg + (long)d * 128 + t * 4;
    atomicAdd(a + 0, v.x);
    atomicAdd(a + 1, v.y);
    atomicAdd(a + 2, v.z);
    atomicAdd(a + 3, v.w);
}

// one edge handled by 16 threads, 4 floats each (64 features)
__global__ __launch_bounds__(256) void scatter64_kernel(const int* __restrict__ src,
                                                        const int* __restrict__ dst,
                                                        const float* __restrict__ x,
                                                        float* __restrict__ agg) {
    unsigned tid = blockIdx.x * 256u + threadIdx.x;
    unsigned e = tid >> 4;
    unsigned t = tid & 15;
    if (e >= N_EDGES) return;
    int s = src[e], d = dst[e];
    float4 v = *(const float4*)(x + (long)s * 64 + t * 4);
    float* a = agg + (long)d * 64 + t * 4;
    atomicAdd(a + 0, v.x);
    atomicAdd(a + 1, v.y);
    atomicAdd(a + 2, v.z);
    atomicAdd(a + 3, v.w);
}

// h1 = relu(feat@Ws1 + (agg1*inv)@Wn1 + b1)   [50000,128]x[128,128]
__global__ __launch_bounds__(256) void gemm1_kernel(const float* __restrict__ feat,
                                                    const float* __restrict__ agg1,
                                                    const float* __restrict__ deg,
                                                    const float* __restrict__ Ws,
                                                    const float* __restrict__ Wn,
                                                    const float* __restrict__ b,
                                                    float* __restrict__ h1) {
    __shared__ float xt[64][33];
    __shared__ float wt[32][128];
    __shared__ float invs[64];
    int tid = threadIdx.x;
    int tj = tid & 31;   // cols 4*tj .. 4*tj+3
    int tn = tid >> 5;   // nodes tn*8 .. tn*8+7
    long nbase = (long)blockIdx.x * 64;
    int nvalid = min(64, N_NODES - (int)nbase);

    if (tid < 64) {
        float dg = (tid < nvalid) ? deg[nbase + tid] : 0.f;
        invs[tid] = (dg > 0.f) ? 1.0f / dg : 0.f;
    }
    __syncthreads();

    float acc[8][4];
#pragma unroll
    for (int i = 0; i < 8; i++)
#pragma unroll
        for (int j = 0; j < 4; j++) acc[i][j] = 0.f;

    for (int pass = 0; pass < 2; ++pass) {
        const float* xsrc = pass ? agg1 : feat;
        const float* wsrc = pass ? Wn : Ws;
        for (int kc = 0; kc < 128; kc += 32) {
            __syncthreads();
            // stage x tile: 64 rows x 32 k
            {
                int q = tid & 7;
                int r0 = tid >> 3;
#pragma unroll
                for (int rr = 0; rr < 2; ++rr) {
                    int r = r0 + rr * 32;
                    float4 v = make_float4(0.f, 0.f, 0.f, 0.f);
                    if (r < nvalid)
                        v = *(const float4*)(xsrc + (nbase + r) * 128 + kc + q * 4);
                    float scale = pass ? invs[r] : 1.0f;
                    xt[r][q * 4 + 0] = v.x * scale;
                    xt[r][q * 4 + 1] = v.y * scale;
                    xt[r][q * 4 + 2] = v.z * scale;
                    xt[r][q * 4 + 3] = v.w * scale;
                }
            }
            // stage W tile: 32 k-rows x 128 cols
            {
                int r = tid >> 3;
                int q = tid & 7;
                const float* wr = wsrc + (long)(kc + r) * 128 + q * 16;
                float4* wdst = (float4*)(&wt[r][q * 16]);
#pragma unroll
                for (int ii = 0; ii < 4; ++ii) wdst[ii] = *(const float4*)(wr + ii * 4);
            }
            __syncthreads();
#pragma unroll
            for (int k = 0; k < 32; ++k) {
                float4 w = *(const float4*)(&wt[k][tj * 4]);
#pragma unroll
                for (int i = 0; i < 8; ++i) {
                    float xv = xt[tn * 8 + i][k];
                    acc[i][0] += xv * w.x;
                    acc[i][1] += xv * w.y;
                    acc[i][2] += xv * w.z;
                    acc[i][3] += xv * w.w;
                }
            }
        }
    }
    float4 bias = *(const float4*)(b + tj * 4);
#pragma unroll
    for (int i = 0; i < 8; ++i) {
        int n = tn * 8 + i;
        if (n < nvalid) {
            float4 o;
            o.x = fmaxf(acc[i][0] + bias.x, 0.f);
            o.y = fmaxf(acc[i][1] + bias.y, 0.f);
            o.z = fmaxf(acc[i][2] + bias.z, 0.f);
            o.w = fmaxf(acc[i][3] + bias.w, 0.f);
            *(float4*)(h1 + (nbase + n) * 128 + tj * 4) = o;
        }
    }
}

// generic [N,128]x[128,64] with optional epilogue add of agg2*inv + bias
// MODE 0: p2 = h1 @ Wn2                (no epilogue extras)
// MODE 1: out = h1 @ Ws2 + agg2*inv + b2
template <int MODE>
__global__ __launch_bounds__(256) void gemm64_kernel(const float* __restrict__ x,
                                                     const float* __restrict__ W,
                                                     const float* __restrict__ agg2,
                                                     const float* __restrict__ deg,
                                                     const float* __restrict__ b,
                                                     float* __restrict__ out) {
    __shared__ float xt[64][33];
    __shared__ float wt[32][64];
    __shared__ float invs[64];
    int tid = threadIdx.x;
    int tj = tid & 15;   // cols 4*tj .. 4*tj+3 (of 64)
    int tn = tid >> 4;   // nodes tn*4 .. tn*4+3
    long nbase = (long)blockIdx.x * 64;
    int nvalid = min(64, N_NODES - (int)nbase);

    if (MODE == 1 && tid < 64) {
        float dg = (tid < nvalid) ? deg[nbase + tid] : 0.f;
        invs[tid] = (dg > 0.f) ? 1.0f / dg : 0.f;
    }
    __syncthreads();

    float acc[4][4];
#pragma unroll
    for (int i = 0; i < 4; i++)
#pragma unroll
        for (int j = 0; j < 4; j++) acc[i][j] = 0.f;

    for (int kc = 0; kc < 128; kc += 32) {
        __syncthreads();
        {
            int q = tid & 7;
            int r0 = tid >> 3;
#pragma unroll
            for (int rr = 0; rr < 2; ++rr) {
                int r = r0 + rr * 32;
                float4 v = make_float4(0.f, 0.f, 0.f, 0.f);
                if (r < nvalid)
                    v = *(const float4*)(x + (nbase + r) * 128 + kc + q * 4);
                xt[r][q * 4 + 0] = v.x;
                xt[r][q * 4 + 1] = v.y;
                xt[r][q * 4 + 2] = v.z;
                xt[r][q * 4 + 3] = v.w;
            }
        }
        {
            int r = tid >> 3;  // k-row 0..31
            int q = tid & 7;   // 2 float4 each
            const float* wr = W + (long)(kc + r) * 64 + q * 8;
            *(float4*)(&wt[r][q * 8 + 0]) = *(const float4*)(wr + 0);
            *(float4*)(&wt[r][q * 8 + 4]) = *(const float4*)(wr + 4);
        }
        __syncthreads();
#pragma unroll
        for (int k = 0; k < 32; ++k) {
            float4 w = *(const float4*)(&wt[k][tj * 4]);
#pragma unroll
            for (int i = 0; i < 4; ++i) {
                float xv = xt[tn * 4 + i][k];
                acc[i][0] += xv * w.x;
                acc[i][1] += xv * w.y;
                acc[i][2] += xv * w.z;
                acc[i][3] += xv * w.w;
            }
        }
    }

    float4 bias = make_float4(0.f, 0.f, 0.f, 0.f);
    if (MODE == 1) bias = *(const float4*)(b + tj * 4);
#pragma unroll
    for (int i = 0; i < 4; ++i) {
        int n = tn * 4 + i;
        if (n < nvalid) {
            float4 o;
            o.x = acc[i][0];
            o.y = acc[i][1];
            o.z = acc[i][2];
            o.w = acc[i][3];
            if (MODE == 1) {
                float iv = invs[n];
                const float4 a2 = *(const float4*)(agg2 + (nbase + n) * 64 + tj * 4);
                o.x = o.x + a2.x * iv + bias.x;
                o.y = o.y + a2.y * iv + bias.y;
                o.z = o.z + a2.z * iv + bias.z;
                o.w = o.w + a2.w * iv + bias.w;
            }
            *(float4*)(out + (nbase + n) * 64 + tj * 4) = o;
        }
    }
}

extern "C" void kernel_launch(void* const* d_in, const int* in_sizes, int n_in,
                              void* d_out, int out_size, void* d_ws, size_t ws_size,
                              hipStream_t stream) {
    const float* feat = (const float*)d_in[0];
    const int* src    = (const int*)d_in[1];
    const int* dst    = (const int*)d_in[2];
    const float* Ws1  = (const float*)d_in[3];
    const float* Wn1  = (const float*)d_in[4];
    const float* b1   = (const float*)d_in[5];
    const float* Ws2  = (const float*)d_in[6];
    const float* Wn2  = (const float*)d_in[7];
    const float* b2   = (const float*)d_in[8];
    float* out = (float*)d_out;

    float* ws   = (float*)d_ws;
    float* deg  = ws + OFF_DEG;
    float* agg1 = ws + OFF_AGG1;
    float* h1   = ws + OFF_H1;
    float* p2   = ws + OFF_P2;
    float* agg2 = ws + OFF_AGG2;

    // zero deg + agg1 (contiguous) and agg2
    hipMemsetAsync(ws, 0, (size_t)(OFF_AGG1 + 50000 * 128) * sizeof(float), stream);
    hipMemsetAsync(agg2, 0, (size_t)(50000 * 64) * sizeof(float), stream);

    // degree
    deg_kernel<<<(N_EDGES + 255) / 256, 256, 0, stream>>>(dst, deg);

    // layer-1 scatter: agg1 += feat[src]
    {
        unsigned total = (unsigned)N_EDGES * 32u;
        scatter128_kernel<<<(total + 255) / 256, 256, 0, stream>>>(src, dst, feat, agg1);
    }

    // layer-1 gemm: h1 = relu(feat@Ws1 + (agg1/deg)@Wn1 + b1)
    gemm1_kernel<<<(N_NODES + 63) / 64, 256, 0, stream>>>(feat, agg1, deg, Ws1, Wn1, b1, h1);

    // p2 = h1 @ Wn2   (aggregate-after-matmul: halves scatter width)
    gemm64_kernel<0><<<(N_NODES + 63) / 64, 256, 0, stream>>>(h1, Wn2, nullptr, nullptr, nullptr, p2);

    // layer-2 scatter: agg2 += p2[src]
    {
        unsigned total = (unsigned)N_EDGES * 16u;
        scatter64_kernel<<<(total + 255) / 256, 256, 0, stream>>>(src, dst, p2, agg2);
    }

    // out = h1@Ws2 + agg2/deg + b2
    gemm64_kernel<1><<<(N_NODES + 63) / 64, 256, 0, stream>>>(h1, Ws2, agg2, deg, b2, out);
}

// Round 3
// 452.835 us; speedup vs baseline: 4.9863x; 4.9863x over previous
//
#include <hip/hip_runtime.h>

#define N_NODES 50000
#define N_EDGES 800000
// IN=128, HID=128, OUT=64

// ---------------- workspace layout ----------------
// ints (4B each), as int offsets into ws:
//   cnt     [50000]   @ 0
//   fillpos [50000]   @ 50000
//   rowptr  [50001]   @ 100000
//   eidx    [800000]  @ 150016
// floats, as float offsets into ws:
//   agg1 [50000*128] @ 950016
//   h1   [50000*128] @ 7350016
//   p2   [50000*64]  @ 13750016
#define IOFF_CNT     0
#define IOFF_FILL    50000
#define IOFF_ROWPTR  100000
#define IOFF_EIDX    150016
#define FOFF_AGG1    950016
#define FOFF_H1      7350016
#define FOFF_P2      13750016

__global__ __launch_bounds__(256) void hist_kernel(const int* __restrict__ dst,
                                                   int* __restrict__ cnt) {
    int e = blockIdx.x * 256 + threadIdx.x;
    if (e < N_EDGES) atomicAdd(&cnt[dst[e]], 1);
}

// single-block exclusive scan of cnt[50000] -> rowptr[50001]
__global__ __launch_bounds__(1024) void scan_kernel(const int* __restrict__ cnt,
                                                    int* __restrict__ rowptr) {
    __shared__ int sh[1024];
    __shared__ int sbase;
    int tid = threadIdx.x;
    if (tid == 0) sbase = 0;
    __syncthreads();
    for (int c = 0; c < N_NODES; c += 1024) {
        int i = c + tid;
        int v = (i < N_NODES) ? cnt[i] : 0;
        sh[tid] = v;
        __syncthreads();
        for (int off = 1; off < 1024; off <<= 1) {
            int t = (tid >= off) ? sh[tid - off] : 0;
            __syncthreads();
            sh[tid] += t;
            __syncthreads();
        }
        int incl = sh[tid];
        int excl = sbase + incl - v;
        if (i < N_NODES) rowptr[i] = excl;
        __syncthreads();
        if (tid == 1023) sbase = excl + v;
        __syncthreads();
    }
    if (tid == 0) rowptr[N_NODES] = sbase;
}

__global__ __launch_bounds__(256) void fill_kernel(const int* __restrict__ src,
                                                   const int* __restrict__ dst,
                                                   const int* __restrict__ rowptr,
                                                   int* __restrict__ fillpos,
                                                   int* __restrict__ eidx) {
    int e = blockIdx.x * 256 + threadIdx.x;
    if (e >= N_EDGES) return;
    int d = dst[e];
    int pos = rowptr[d] + atomicAdd(&fillpos[d], 1);
    eidx[pos] = src[e];
}

// one wave (64 lanes) per node; lane handles 2 columns (float2 = 8B)
// writes agg = mean of neighbor rows (128 cols)
__global__ __launch_bounds__(256) void gather128_kernel(const int* __restrict__ rowptr,
                                                        const int* __restrict__ eidx,
                                                        const float* __restrict__ x,
                                                        float* __restrict__ agg) {
    int node = blockIdx.x * 4 + (threadIdx.x >> 6);
    int lane = threadIdx.x & 63;
    if (node >= N_NODES) return;
    int beg = rowptr[node], end = rowptr[node + 1];
    float2 a0 = {0.f, 0.f}, a1 = {0.f, 0.f};
    int e = beg;
    for (; e + 1 < end; e += 2) {
        int s0 = eidx[e], s1 = eidx[e + 1];
        float2 v0 = *(const float2*)(x + (long)s0 * 128 + lane * 2);
        float2 v1 = *(const float2*)(x + (long)s1 * 128 + lane * 2);
        a0.x += v0.x; a0.y += v0.y;
        a1.x += v1.x; a1.y += v1.y;
    }
    if (e < end) {
        int s0 = eidx[e];
        float2 v0 = *(const float2*)(x + (long)s0 * 128 + lane * 2);
        a0.x += v0.x; a0.y += v0.y;
    }
    float inv = (end > beg) ? 1.0f / (float)(end - beg) : 0.f;
    float2 o;
    o.x = (a0.x + a1.x) * inv;
    o.y = (a0.y + a1.y) * inv;
    *(float2*)(agg + (long)node * 128 + lane * 2) = o;
}

// one wave per node; lane handles 1 column of 64; out[node] += mean(p2[neigh])
__global__ __launch_bounds__(256) void gather64_add_kernel(const int* __restrict__ rowptr,
                                                           const int* __restrict__ eidx,
                                                           const float* __restrict__ p2,
                                                           float* __restrict__ out) {
    int node = blockIdx.x * 4 + (threadIdx.x >> 6);
    int lane = threadIdx.x & 63;
    if (node >= N_NODES) return;
    int beg = rowptr[node], end = rowptr[node + 1];
    float a0 = 0.f, a1 = 0.f;
    int e = beg;
    for (; e + 1 < end; e += 2) {
        int s0 = eidx[e], s1 = eidx[e + 1];
        a0 += p2[(long)s0 * 64 + lane];
        a1 += p2[(long)s1 * 64 + lane];
    }
    if (e < end) a0 += p2[(long)eidx[e] * 64 + lane];
    float inv = (end > beg) ? 1.0f / (float)(end - beg) : 0.f;
    out[(long)node * 64 + lane] += (a0 + a1) * inv;
}

// h1 = relu(feat@Ws1 + agg1@Wn1 + b1)   [50000,128]x[128,128] (x2 weight mats)
__global__ __launch_bounds__(256) void gemm1_kernel(const float* __restrict__ feat,
                                                    const float* __restrict__ agg1,
                                                    const float* __restrict__ Ws,
                                                    const float* __restrict__ Wn,
                                                    const float* __restrict__ b,
                                                    float* __restrict__ h1) {
    __shared__ float xt[64][33];
    __shared__ float wt[32][128];
    int tid = threadIdx.x;
    int tj = tid & 31;   // cols 4*tj .. 4*tj+3
    int tn = tid >> 5;   // nodes tn*8 .. tn*8+7
    long nbase = (long)blockIdx.x * 64;
    int nvalid = min(64, N_NODES - (int)nbase);

    float acc[8][4];
#pragma unroll
    for (int i = 0; i < 8; i++)
#pragma unroll
        for (int j = 0; j < 4; j++) acc[i][j] = 0.f;

    for (int pass = 0; pass < 2; ++pass) {
        const float* xsrc = pass ? agg1 : feat;
        const float* wsrc = pass ? Wn : Ws;
        for (int kc = 0; kc < 128; kc += 32) {
            __syncthreads();
            {
                int q = tid & 7;
                int r0 = tid >> 3;
#pragma unroll
                for (int rr = 0; rr < 2; ++rr) {
                    int r = r0 + rr * 32;
                    float4 v = make_float4(0.f, 0.f, 0.f, 0.f);
                    if (r < nvalid)
                        v = *(const float4*)(xsrc + (nbase + r) * 128 + kc + q * 4);
                    xt[r][q * 4 + 0] = v.x;
                    xt[r][q * 4 + 1] = v.y;
                    xt[r][q * 4 + 2] = v.z;
                    xt[r][q * 4 + 3] = v.w;
                }
            }
            {
                int r = tid >> 3;
                int q = tid & 7;
                const float* wr = wsrc + (long)(kc + r) * 128 + q * 16;
                float4* wdst = (float4*)(&wt[r][q * 16]);
#pragma unroll
                for (int ii = 0; ii < 4; ++ii) wdst[ii] = *(const float4*)(wr + ii * 4);
            }
            __syncthreads();
#pragma unroll
            for (int k = 0; k < 32; ++k) {
                float4 w = *(const float4*)(&wt[k][tj * 4]);
#pragma unroll
                for (int i = 0; i < 8; ++i) {
                    float xv = xt[tn * 8 + i][k];
                    acc[i][0] += xv * w.x;
                    acc[i][1] += xv * w.y;
                    acc[i][2] += xv * w.z;
                    acc[i][3] += xv * w.w;
                }
            }
        }
    }
    float4 bias = *(const float4*)(b + tj * 4);
#pragma unroll
    for (int i = 0; i < 8; ++i) {
        int n = tn * 8 + i;
        if (n < nvalid) {
            float4 o;
            o.x = fmaxf(acc[i][0] + bias.x, 0.f);
            o.y = fmaxf(acc[i][1] + bias.y, 0.f);
            o.z = fmaxf(acc[i][2] + bias.z, 0.f);
            o.w = fmaxf(acc[i][3] + bias.w, 0.f);
            *(float4*)(h1 + (nbase + n) * 128 + tj * 4) = o;
        }
    }
}

// [N,128]x[128,64]
// MODE 0: out = x @ W            (p2 = h1 @ Wn2)
// MODE 1: out = x @ W + b        (out = h1 @ Ws2 + b2; gather64_add adds neigh term)
template <int MODE>
__global__ __launch_bounds__(256) void gemm64_kernel(const float* __restrict__ x,
                                                     const float* __restrict__ W,
                                                     const float* __restrict__ b,
                                                     float* __restrict__ out) {
    __shared__ float xt[64][33];
    __shared__ float wt[32][64];
    int tid = threadIdx.x;
    int tj = tid & 15;   // cols 4*tj .. 4*tj+3 (of 64)
    int tn = tid >> 4;   // nodes tn*4 .. tn*4+3
    long nbase = (long)blockIdx.x * 64;
    int nvalid = min(64, N_NODES - (int)nbase);

    float acc[4][4];
#pragma unroll
    for (int i = 0; i < 4; i++)
#pragma unroll
        for (int j = 0; j < 4; j++) acc[i][j] = 0.f;

    for (int kc = 0; kc < 128; kc += 32) {
        __syncthreads();
        {
            int q = tid & 7;
            int r0 = tid >> 3;
#pragma unroll
            for (int rr = 0; rr < 2; ++rr) {
                int r = r0 + rr * 32;
                float4 v = make_float4(0.f, 0.f, 0.f, 0.f);
                if (r < nvalid)
                    v = *(const float4*)(x + (nbase + r) * 128 + kc + q * 4);
                xt[r][q * 4 + 0] = v.x;
                xt[r][q * 4 + 1] = v.y;
                xt[r][q * 4 + 2] = v.z;
                xt[r][q * 4 + 3] = v.w;
            }
        }
        {
            int r = tid >> 3;
            int q = tid & 7;
            const float* wr = W + (long)(kc + r) * 64 + q * 8;
            *(float4*)(&wt[r][q * 8 + 0]) = *(const float4*)(wr + 0);
            *(float4*)(&wt[r][q * 8 + 4]) = *(const float4*)(wr + 4);
        }
        __syncthreads();
#pragma unroll
        for (int k = 0; k < 32; ++k) {
            float4 w = *(const float4*)(&wt[k][tj * 4]);
#pragma unroll
            for (int i = 0; i < 4; ++i) {
                float xv = xt[tn * 4 + i][k];
                acc[i][0] += xv * w.x;
                acc[i][1] += xv * w.y;
                acc[i][2] += xv * w.z;
                acc[i][3] += xv * w.w;
            }
        }
    }

    float4 bias = make_float4(0.f, 0.f, 0.f, 0.f);
    if (MODE == 1) bias = *(const float4*)(b + tj * 4);
#pragma unroll
    for (int i = 0; i < 4; ++i) {
        int n = tn * 4 + i;
        if (n < nvalid) {
            float4 o;
            o.x = acc[i][0] + bias.x;
            o.y = acc[i][1] + bias.y;
            o.z = acc[i][2] + bias.z;
            o.w = acc[i][3] + bias.w;
            *(float4*)(out + (nbase + n) * 64 + tj * 4) = o;
        }
    }
}

extern "C" void kernel_launch(void* const* d_in, const int* in_sizes, int n_in,
                              void* d_out, int out_size, void* d_ws, size_t ws_size,
                              hipStream_t stream) {
    const float* feat = (const float*)d_in[0];
    const int* src    = (const int*)d_in[1];
    const int* dst    = (const int*)d_in[2];
    const float* Ws1  = (const float*)d_in[3];
    const float* Wn1  = (const float*)d_in[4];
    const float* b1   = (const float*)d_in[5];
    const float* Ws2  = (const float*)d_in[6];
    const float* Wn2  = (const float*)d_in[7];
    const float* b2   = (const float*)d_in[8];
    float* out = (float*)d_out;

    int* wsi   = (int*)d_ws;
    float* wsf = (float*)d_ws;
    int* cnt     = wsi + IOFF_CNT;
    int* fillpos = wsi + IOFF_FILL;
    int* rowptr  = wsi + IOFF_ROWPTR;
    int* eidx    = wsi + IOFF_EIDX;
    float* agg1  = wsf + FOFF_AGG1;
    float* h1    = wsf + FOFF_H1;
    float* p2    = wsf + FOFF_P2;

    // zero cnt + fillpos (contiguous 100000 ints)
    hipMemsetAsync(wsi, 0, 100000 * sizeof(int), stream);

    // ---- build CSR (dst-sorted) ----
    hist_kernel<<<(N_EDGES + 255) / 256, 256, 0, stream>>>(dst, cnt);
    scan_kernel<<<1, 1024, 0, stream>>>(cnt, rowptr);
    fill_kernel<<<(N_EDGES + 255) / 256, 256, 0, stream>>>(src, dst, rowptr, fillpos, eidx);

    // ---- layer 1 ----
    gather128_kernel<<<(N_NODES + 3) / 4, 256, 0, stream>>>(rowptr, eidx, feat, agg1);
    gemm1_kernel<<<(N_NODES + 63) / 64, 256, 0, stream>>>(feat, agg1, Ws1, Wn1, b1, h1);

    // ---- layer 2 (aggregate-after-matmul) ----
    gemm64_kernel<0><<<(N_NODES + 63) / 64, 256, 0, stream>>>(h1, Wn2, nullptr, p2);
    gemm64_kernel<1><<<(N_NODES + 63) / 64, 256, 0, stream>>>(h1, Ws2, b2, out);
    gather64_add_kernel<<<(N_NODES + 3) / 4, 256, 0, stream>>>(rowptr, eidx, p2, out);
}

// Round 4
// 376.718 us; speedup vs baseline: 5.9938x; 1.2021x over previous
//
#include <hip/hip_runtime.h>

#define N_NODES 50000
#define N_EDGES 800000
// IN=128, HID=128, OUT=64

typedef unsigned short ushort_t;
typedef unsigned int uint_t;

// ---------------- workspace layout ----------------
// int region (int offsets):
//   cnt     [50000]   @ 0
//   fillpos [50000]   @ 50000
//   rowptr  [50001]   @ 100000
//   eidx    [800000]  @ 150016
//   partial [64]      @ 950016
// bf16 region (ushort offsets into ws):
//   featb [50000*128] @ 2000000
//   agg1b [50000*128] @ 8400000
//   h1b   [50000*128] @ 14800000
//   p2b   [50000*64]  @ 21200000
#define IOFF_CNT     0
#define IOFF_FILL    50000
#define IOFF_ROWPTR  100000
#define IOFF_EIDX    150016
#define IOFF_PART    950016
#define UOFF_FEATB   2000000
#define UOFF_AGG1B   8400000
#define UOFF_H1B     14800000
#define UOFF_P2B     21200000

__device__ __forceinline__ float bf2f(uint_t u) {
    return __uint_as_float(u << 16);
}
__device__ __forceinline__ uint_t f2bf(float f) {
    uint_t x = __float_as_uint(f);
    return (x + 0x7FFFu + ((x >> 16) & 1u)) >> 16;  // RNE
}

__global__ __launch_bounds__(256) void hist_kernel(const int* __restrict__ dst,
                                                   int* __restrict__ cnt) {
    int e = blockIdx.x * 256 + threadIdx.x;
    if (e < N_EDGES) atomicAdd(&cnt[dst[e]], 1);
}

// phase A: per-block scan of 1024 elements, local-exclusive into rowptr, total into partial[b]
__global__ __launch_bounds__(1024) void scan_part(const int* __restrict__ cnt,
                                                  int* __restrict__ rowptr,
                                                  int* __restrict__ partial) {
    __shared__ int sh[1024];
    int b = blockIdx.x, tid = threadIdx.x;
    int i = b * 1024 + tid;
    int v = (i < N_NODES) ? cnt[i] : 0;
    sh[tid] = v;
    __syncthreads();
    for (int off = 1; off < 1024; off <<= 1) {
        int t = (tid >= off) ? sh[tid - off] : 0;
        __syncthreads();
        sh[tid] += t;
        __syncthreads();
    }
    if (i < N_NODES) rowptr[i] = sh[tid] - v;  // local exclusive
    if (tid == 1023) partial[b] = sh[1023];
}

// phase B: one wave scans the 49 block totals -> exclusive bases; writes grand total
__global__ __launch_bounds__(64) void scan_top(int* __restrict__ partial,
                                               int* __restrict__ rowptr) {
    int l = threadIdx.x;
    int nblk = (N_NODES + 1023) / 1024;
    int v = (l < nblk) ? partial[l] : 0;
    int incl = v;
    for (int off = 1; off < 64; off <<= 1) {
        int t = __shfl_up(incl, off);
        if (l >= off) incl += t;
    }
    partial[l] = incl - v;  // exclusive base
    if (l == 63) rowptr[N_NODES] = incl;  // grand total
}

// phase C: add block bases
__global__ __launch_bounds__(1024) void scan_add(int* __restrict__ rowptr,
                                                 const int* __restrict__ partial) {
    int i = blockIdx.x * 1024 + threadIdx.x;
    if (i < N_NODES) rowptr[i] += partial[blockIdx.x];
}

__global__ __launch_bounds__(256) void fill_kernel(const int* __restrict__ src,
                                                   const int* __restrict__ dst,
                                                   const int* __restrict__ rowptr,
                                                   int* __restrict__ fillpos,
                                                   int* __restrict__ eidx) {
    int e = blockIdx.x * 256 + threadIdx.x;
    if (e >= N_EDGES) return;
    int d = dst[e];
    int pos = rowptr[d] + atomicAdd(&fillpos[d], 1);
    eidx[pos] = src[e];
}

// f32 -> bf16 conversion, 4 floats/thread
__global__ __launch_bounds__(256) void cvt_kernel(const float* __restrict__ x,
                                                  ushort_t* __restrict__ y, int n4) {
    int i = blockIdx.x * 256 + threadIdx.x;
    if (i >= n4) return;
    float4 v = ((const float4*)x)[i];
    uint2 o;
    o.x = f2bf(v.x) | (f2bf(v.y) << 16);
    o.y = f2bf(v.z) | (f2bf(v.w) << 16);
    ((uint2*)y)[i] = o;
}

// one wave per node; lane handles 2 cols (bf16x2 = 4B); agg1b = mean of neighbor rows
__global__ __launch_bounds__(256) void gather128_kernel(const int* __restrict__ rowptr,
                                                        const int* __restrict__ eidx,
                                                        const ushort_t* __restrict__ xb,
                                                        ushort_t* __restrict__ aggb) {
    int node = blockIdx.x * 4 + (threadIdx.x >> 6);
    int lane = threadIdx.x & 63;
    if (node >= N_NODES) return;
    int beg = rowptr[node], end = rowptr[node + 1];
    float ax0 = 0.f, ay0 = 0.f, ax1 = 0.f, ay1 = 0.f;
    int e = beg;
    for (; e + 1 < end; e += 2) {
        int s0 = eidx[e], s1 = eidx[e + 1];
        uint_t v0 = *(const uint_t*)(xb + (long)s0 * 128 + lane * 2);
        uint_t v1 = *(const uint_t*)(xb + (long)s1 * 128 + lane * 2);
        ax0 += bf2f(v0 & 0xffffu); ay0 += bf2f(v0 >> 16);
        ax1 += bf2f(v1 & 0xffffu); ay1 += bf2f(v1 >> 16);
    }
    if (e < end) {
        uint_t v0 = *(const uint_t*)(xb + (long)eidx[e] * 128 + lane * 2);
        ax0 += bf2f(v0 & 0xffffu); ay0 += bf2f(v0 >> 16);
    }
    float inv = (end > beg) ? 1.0f / (float)(end - beg) : 0.f;
    uint_t o = f2bf((ax0 + ax1) * inv) | (f2bf((ay0 + ay1) * inv) << 16);
    *(uint_t*)(aggb + (long)node * 128 + lane * 2) = o;
}

// one wave per node; lane = 1 col of 64; out[node] += mean(p2b[neigh]) (f32 out)
__global__ __launch_bounds__(256) void gather64_add_kernel(const int* __restrict__ rowptr,
                                                           const int* __restrict__ eidx,
                                                           const ushort_t* __restrict__ p2b,
                                                           float* __restrict__ out) {
    int node = blockIdx.x * 4 + (threadIdx.x >> 6);
    int lane = threadIdx.x & 63;
    if (node >= N_NODES) return;
    int beg = rowptr[node], end = rowptr[node + 1];
    float a0 = 0.f, a1 = 0.f;
    int e = beg;
    for (; e + 1 < end; e += 2) {
        a0 += bf2f((uint_t)p2b[(long)eidx[e] * 64 + lane]);
        a1 += bf2f((uint_t)p2b[(long)eidx[e + 1] * 64 + lane]);
    }
    if (e < end) a0 += bf2f((uint_t)p2b[(long)eidx[e] * 64 + lane]);
    float inv = (end > beg) ? 1.0f / (float)(end - beg) : 0.f;
    out[(long)node * 64 + lane] += (a0 + a1) * inv;
}

// h1b = bf16(relu(featb@Ws1 + agg1b@Wn1 + b1))   [50000,128]x[128,128] x2
__global__ __launch_bounds__(256) void gemm1_kernel(const ushort_t* __restrict__ featb,
                                                    const ushort_t* __restrict__ agg1b,
                                                    const float* __restrict__ Ws,
                                                    const float* __restrict__ Wn,
                                                    const float* __restrict__ b,
                                                    ushort_t* __restrict__ h1b) {
    __shared__ float xt[64][33];
    __shared__ float wt[32][128];
    int tid = threadIdx.x;
    int tj = tid & 31;   // cols 4*tj..+3
    int tn = tid >> 5;   // rows tn*8..+7
    long nbase = (long)blockIdx.x * 64;
    int nvalid = min(64, N_NODES - (int)nbase);

    float acc[8][4];
#pragma unroll
    for (int i = 0; i < 8; i++)
#pragma unroll
        for (int j = 0; j < 4; j++) acc[i][j] = 0.f;

    for (int pass = 0; pass < 2; ++pass) {
        const ushort_t* xsrc = pass ? agg1b : featb;
        const float* wsrc = pass ? Wn : Ws;
        for (int kc = 0; kc < 128; kc += 32) {
            __syncthreads();
            {
                int q = tid & 7;
                int r0 = tid >> 3;
#pragma unroll
                for (int rr = 0; rr < 2; ++rr) {
                    int r = r0 + rr * 32;
                    uint2 v = make_uint2(0, 0);
                    if (r < nvalid)
                        v = *(const uint2*)(xsrc + (nbase + r) * 128 + kc + q * 4);
                    xt[r][q * 4 + 0] = bf2f(v.x & 0xffffu);
                    xt[r][q * 4 + 1] = bf2f(v.x >> 16);
                    xt[r][q * 4 + 2] = bf2f(v.y & 0xffffu);
                    xt[r][q * 4 + 3] = bf2f(v.y >> 16);
                }
            }
            {
                int r = tid >> 3;
                int q = tid & 7;
                const float* wr = wsrc + (long)(kc + r) * 128 + q * 16;
                float4* wdst = (float4*)(&wt[r][q * 16]);
#pragma unroll
                for (int ii = 0; ii < 4; ++ii) wdst[ii] = *(const float4*)(wr + ii * 4);
            }
            __syncthreads();
#pragma unroll
            for (int k = 0; k < 32; ++k) {
                float4 w = *(const float4*)(&wt[k][tj * 4]);
#pragma unroll
                for (int i = 0; i < 8; ++i) {
                    float xv = xt[tn * 8 + i][k];
                    acc[i][0] += xv * w.x;
                    acc[i][1] += xv * w.y;
                    acc[i][2] += xv * w.z;
                    acc[i][3] += xv * w.w;
                }
            }
        }
    }
    float4 bias = *(const float4*)(b + tj * 4);
#pragma unroll
    for (int i = 0; i < 8; ++i) {
        int n = tn * 8 + i;
        if (n < nvalid) {
            float o0 = fmaxf(acc[i][0] + bias.x, 0.f);
            float o1 = fmaxf(acc[i][1] + bias.y, 0.f);
            float o2 = fmaxf(acc[i][2] + bias.z, 0.f);
            float o3 = fmaxf(acc[i][3] + bias.w, 0.f);
            uint2 o;
            o.x = f2bf(o0) | (f2bf(o1) << 16);
            o.y = f2bf(o2) | (f2bf(o3) << 16);
            *(uint2*)(h1b + (nbase + n) * 128 + tj * 4) = o;
        }
    }
}

// [N,128]x[128,64] from bf16 x
// MODE 0: p2b = bf16(x @ W)
// MODE 1: out(f32) = x @ W + b
template <int MODE>
__global__ __launch_bounds__(256) void gemm64_kernel(const ushort_t* __restrict__ xb,
                                                     const float* __restrict__ W,
                                                     const float* __restrict__ b,
                                                     ushort_t* __restrict__ outb,
                                                     float* __restrict__ outf) {
    __shared__ float xt[64][33];
    __shared__ float wt[32][64];
    int tid = threadIdx.x;
    int tj = tid & 15;   // cols 4*tj..+3 (of 64)
    int tn = tid >> 4;   // rows tn*4..+3
    long nbase = (long)blockIdx.x * 64;
    int nvalid = min(64, N_NODES - (int)nbase);

    float acc[4][4];
#pragma unroll
    for (int i = 0; i < 4; i++)
#pragma unroll
        for (int j = 0; j < 4; j++) acc[i][j] = 0.f;

    for (int kc = 0; kc < 128; kc += 32) {
        __syncthreads();
        {
            int q = tid & 7;
            int r0 = tid >> 3;
#pragma unroll
            for (int rr = 0; rr < 2; ++rr) {
                int r = r0 + rr * 32;
                uint2 v = make_uint2(0, 0);
                if (r < nvalid)
                    v = *(const uint2*)(xb + (nbase + r) * 128 + kc + q * 4);
                xt[r][q * 4 + 0] = bf2f(v.x & 0xffffu);
                xt[r][q * 4 + 1] = bf2f(v.x >> 16);
                xt[r][q * 4 + 2] = bf2f(v.y & 0xffffu);
                xt[r][q * 4 + 3] = bf2f(v.y >> 16);
            }
        }
        {
            int r = tid >> 3;
            int q = tid & 7;
            const float* wr = W + (long)(kc + r) * 64 + q * 8;
            *(float4*)(&wt[r][q * 8 + 0]) = *(const float4*)(wr + 0);
            *(float4*)(&wt[r][q * 8 + 4]) = *(const float4*)(wr + 4);
        }
        __syncthreads();
#pragma unroll
        for (int k = 0; k < 32; ++k) {
            float4 w = *(const float4*)(&wt[k][tj * 4]);
#pragma unroll
            for (int i = 0; i < 4; ++i) {
                float xv = xt[tn * 4 + i][k];
                acc[i][0] += xv * w.x;
                acc[i][1] += xv * w.y;
                acc[i][2] += xv * w.z;
                acc[i][3] += xv * w.w;
            }
        }
    }

    float4 bias = make_float4(0.f, 0.f, 0.f, 0.f);
    if (MODE == 1) bias = *(const float4*)(b + tj * 4);
#pragma unroll
    for (int i = 0; i < 4; ++i) {
        int n = tn * 4 + i;
        if (n < nvalid) {
            if (MODE == 0) {
                uint2 o;
                o.x = f2bf(acc[i][0]) | (f2bf(acc[i][1]) << 16);
                o.y = f2bf(acc[i][2]) | (f2bf(acc[i][3]) << 16);
                *(uint2*)(outb + (nbase + n) * 64 + tj * 4) = o;
            } else {
                float4 o;
                o.x = acc[i][0] + bias.x;
                o.y = acc[i][1] + bias.y;
                o.z = acc[i][2] + bias.z;
                o.w = acc[i][3] + bias.w;
                *(float4*)(outf + (nbase + n) * 64 + tj * 4) = o;
            }
        }
    }
}

extern "C" void kernel_launch(void* const* d_in, const int* in_sizes, int n_in,
                              void* d_out, int out_size, void* d_ws, size_t ws_size,
                              hipStream_t stream) {
    const float* feat = (const float*)d_in[0];
    const int* src    = (const int*)d_in[1];
    const int* dst    = (const int*)d_in[2];
    const float* Ws1  = (const float*)d_in[3];
    const float* Wn1  = (const float*)d_in[4];
    const float* b1   = (const float*)d_in[5];
    const float* Ws2  = (const float*)d_in[6];
    const float* Wn2  = (const float*)d_in[7];
    const float* b2   = (const float*)d_in[8];
    float* out = (float*)d_out;

    int* wsi      = (int*)d_ws;
    ushort_t* wsu = (ushort_t*)d_ws;
    int* cnt      = wsi + IOFF_CNT;
    int* fillpos  = wsi + IOFF_FILL;
    int* rowptr   = wsi + IOFF_ROWPTR;
    int* eidx     = wsi + IOFF_EIDX;
    int* partial  = wsi + IOFF_PART;
    ushort_t* featb = wsu + UOFF_FEATB;
    ushort_t* agg1b = wsu + UOFF_AGG1B;
    ushort_t* h1b   = wsu + UOFF_H1B;
    ushort_t* p2b   = wsu + UOFF_P2B;

    // zero cnt + fillpos (contiguous 100000 ints)
    hipMemsetAsync(wsi, 0, 100000 * sizeof(int), stream);

    // feat -> bf16 (independent of CSR build)
    cvt_kernel<<<(N_NODES * 128 / 4 + 255) / 256, 256, 0, stream>>>(feat, featb, N_NODES * 128 / 4);

    // ---- build CSR (dst-sorted) ----
    hist_kernel<<<(N_EDGES + 255) / 256, 256, 0, stream>>>(dst, cnt);
    {
        int nblk = (N_NODES + 1023) / 1024;
        scan_part<<<nblk, 1024, 0, stream>>>(cnt, rowptr, partial);
        scan_top<<<1, 64, 0, stream>>>(partial, rowptr);
        scan_add<<<nblk, 1024, 0, stream>>>(rowptr, partial);
    }
    fill_kernel<<<(N_EDGES + 255) / 256, 256, 0, stream>>>(src, dst, rowptr, fillpos, eidx);

    // ---- layer 1 ----
    gather128_kernel<<<(N_NODES + 3) / 4, 256, 0, stream>>>(rowptr, eidx, featb, agg1b);
    gemm1_kernel<<<(N_NODES + 63) / 64, 256, 0, stream>>>(featb, agg1b, Ws1, Wn1, b1, h1b);

    // ---- layer 2 (aggregate-after-matmul) ----
    gemm64_kernel<0><<<(N_NODES + 63) / 64, 256, 0, stream>>>(h1b, Wn2, nullptr, p2b, nullptr);
    gemm64_kernel<1><<<(N_NODES + 63) / 64, 256, 0, stream>>>(h1b, Ws2, b2, nullptr, out);
    gather64_add_kernel<<<(N_NODES + 3) / 4, 256, 0, stream>>>(rowptr, eidx, p2b, out);
}

// Round 5
// 321.005 us; speedup vs baseline: 7.0341x; 1.1736x over previous
//
#include <hip/hip_runtime.h>

#define N_NODES 50000
#define N_EDGES 800000
// IN=128, HID=128, OUT=64

typedef unsigned short ushort_t;
typedef unsigned int uint_t;
typedef __attribute__((ext_vector_type(8))) short bf16x8;
typedef __attribute__((ext_vector_type(4))) float f32x4;

// ---------------- workspace layout ----------------
// int region (int offsets):
//   cnt     [50000]   @ 0
//   fillpos [50000]   @ 50000
//   rowptr  [50001]   @ 100000
//   eidx    [800000]  @ 150016
//   partial [64]      @ 950016
// bf16 region (ushort offsets into ws):
//   wT    [49152]     @ 1900672   (WsT1 16384 | WnT1 16384 | WnT2 8192 | WsT2 8192)
//   featb [50000*128] @ 2000000
//   agg1b [50000*128] @ 8400000
//   h1b   [50000*128] @ 14800000
//   p2b   [50000*64]  @ 21200000
#define IOFF_CNT     0
#define IOFF_FILL    50000
#define IOFF_ROWPTR  100000
#define IOFF_EIDX    150016
#define IOFF_PART    950016
#define UOFF_WT      1900672
#define UOFF_FEATB   2000000
#define UOFF_AGG1B   8400000
#define UOFF_H1B     14800000
#define UOFF_P2B     21200000

__device__ __forceinline__ float bf2f(uint_t u) {
    return __uint_as_float(u << 16);
}
__device__ __forceinline__ uint_t f2bf(float f) {
    uint_t x = __float_as_uint(f);
    return (x + 0x7FFFu + ((x >> 16) & 1u)) >> 16;  // RNE
}

__global__ __launch_bounds__(256) void hist_kernel(const int* __restrict__ dst,
                                                   int* __restrict__ cnt) {
    int e = blockIdx.x * 256 + threadIdx.x;
    if (e < N_EDGES) atomicAdd(&cnt[dst[e]], 1);
}

__global__ __launch_bounds__(1024) void scan_part(const int* __restrict__ cnt,
                                                  int* __restrict__ rowptr,
                                                  int* __restrict__ partial) {
    __shared__ int sh[1024];
    int b = blockIdx.x, tid = threadIdx.x;
    int i = b * 1024 + tid;
    int v = (i < N_NODES) ? cnt[i] : 0;
    sh[tid] = v;
    __syncthreads();
    for (int off = 1; off < 1024; off <<= 1) {
        int t = (tid >= off) ? sh[tid - off] : 0;
        __syncthreads();
        sh[tid] += t;
        __syncthreads();
    }
    if (i < N_NODES) rowptr[i] = sh[tid] - v;  // local exclusive
    if (tid == 1023) partial[b] = sh[1023];
}

__global__ __launch_bounds__(64) void scan_top(int* __restrict__ partial,
                                               int* __restrict__ rowptr) {
    int l = threadIdx.x;
    int nblk = (N_NODES + 1023) / 1024;
    int v = (l < nblk) ? partial[l] : 0;
    int incl = v;
    for (int off = 1; off < 64; off <<= 1) {
        int t = __shfl_up(incl, off);
        if (l >= off) incl += t;
    }
    partial[l] = incl - v;  // exclusive base
    if (l == 63) rowptr[N_NODES] = incl;
}

__global__ __launch_bounds__(1024) void scan_add(int* __restrict__ rowptr,
                                                 const int* __restrict__ partial) {
    int i = blockIdx.x * 1024 + threadIdx.x;
    if (i < N_NODES) rowptr[i] += partial[blockIdx.x];
}

__global__ __launch_bounds__(256) void fill_kernel(const int* __restrict__ src,
                                                   const int* __restrict__ dst,
                                                   const int* __restrict__ rowptr,
                                                   int* __restrict__ fillpos,
                                                   int* __restrict__ eidx) {
    int e = blockIdx.x * 256 + threadIdx.x;
    if (e >= N_EDGES) return;
    int d = dst[e];
    int pos = rowptr[d] + atomicAdd(&fillpos[d], 1);
    eidx[pos] = src[e];
}

// f32 -> bf16, 4 floats/thread
__global__ __launch_bounds__(256) void cvt_kernel(const float* __restrict__ x,
                                                  ushort_t* __restrict__ y, int n4) {
    int i = blockIdx.x * 256 + threadIdx.x;
    if (i >= n4) return;
    float4 v = ((const float4*)x)[i];
    uint2 o;
    o.x = f2bf(v.x) | (f2bf(v.y) << 16);
    o.y = f2bf(v.z) | (f2bf(v.w) << 16);
    ((uint2*)y)[i] = o;
}

// transpose+convert all 4 weight mats into wT (bf16):
// [0,16384): WsT1[n][k]  from Ws1[k*128+n]   (128x128)
// [16384,32768): WnT1    from Wn1[k*128+n]
// [32768,40960): WnT2[n][k] from Wn2[k*64+n] (64 rows n, 128 k)
// [40960,49152): WsT2    from Ws2[k*64+n]
__global__ __launch_bounds__(256) void wprep_kernel(const float* __restrict__ Ws1,
                                                    const float* __restrict__ Wn1,
                                                    const float* __restrict__ Ws2,
                                                    const float* __restrict__ Wn2,
                                                    ushort_t* __restrict__ wT) {
    int i = blockIdx.x * 256 + threadIdx.x;
    if (i >= 49152) return;
    float v;
    if (i < 16384) {
        int n = i >> 7, k = i & 127;
        v = Ws1[k * 128 + n];
    } else if (i < 32768) {
        int j = i - 16384, n = j >> 7, k = j & 127;
        v = Wn1[k * 128 + n];
    } else if (i < 40960) {
        int j = i - 32768, n = j >> 7, k = j & 127;
        v = Wn2[k * 64 + n];
    } else {
        int j = i - 40960, n = j >> 7, k = j & 127;
        v = Ws2[k * 64 + n];
    }
    wT[i] = (ushort_t)f2bf(v);
}

// one wave per node; lane handles 2 cols (bf16x2 = 4B); agg1b = mean of neighbor rows
__global__ __launch_bounds__(256) void gather128_kernel(const int* __restrict__ rowptr,
                                                        const int* __restrict__ eidx,
                                                        const ushort_t* __restrict__ xb,
                                                        ushort_t* __restrict__ aggb) {
    int node = blockIdx.x * 4 + (threadIdx.x >> 6);
    int lane = threadIdx.x & 63;
    if (node >= N_NODES) return;
    int beg = rowptr[node], end = rowptr[node + 1];
    float ax0 = 0.f, ay0 = 0.f, ax1 = 0.f, ay1 = 0.f;
    int e = beg;
    for (; e + 1 < end; e += 2) {
        int s0 = eidx[e], s1 = eidx[e + 1];
        uint_t v0 = *(const uint_t*)(xb + (long)s0 * 128 + lane * 2);
        uint_t v1 = *(const uint_t*)(xb + (long)s1 * 128 + lane * 2);
        ax0 += bf2f(v0 & 0xffffu); ay0 += bf2f(v0 >> 16);
        ax1 += bf2f(v1 & 0xffffu); ay1 += bf2f(v1 >> 16);
    }
    if (e < end) {
        uint_t v0 = *(const uint_t*)(xb + (long)eidx[e] * 128 + lane * 2);
        ax0 += bf2f(v0 & 0xffffu); ay0 += bf2f(v0 >> 16);
    }
    float inv = (end > beg) ? 1.0f / (float)(end - beg) : 0.f;
    uint_t o = f2bf((ax0 + ax1) * inv) | (f2bf((ay0 + ay1) * inv) << 16);
    *(uint_t*)(aggb + (long)node * 128 + lane * 2) = o;
}

// one wave per node; lane = 1 col of 64; out[node] += mean(p2b[neigh]) (f32 out)
__global__ __launch_bounds__(256) void gather64_add_kernel(const int* __restrict__ rowptr,
                                                           const int* __restrict__ eidx,
                                                           const ushort_t* __restrict__ p2b,
                                                           float* __restrict__ out) {
    int node = blockIdx.x * 4 + (threadIdx.x >> 6);
    int lane = threadIdx.x & 63;
    if (node >= N_NODES) return;
    int beg = rowptr[node], end = rowptr[node + 1];
    float a0 = 0.f, a1 = 0.f;
    int e = beg;
    for (; e + 1 < end; e += 2) {
        a0 += bf2f((uint_t)p2b[(long)eidx[e] * 64 + lane]);
        a1 += bf2f((uint_t)p2b[(long)eidx[e + 1] * 64 + lane]);
    }
    if (e < end) a0 += bf2f((uint_t)p2b[(long)eidx[e] * 64 + lane]);
    float inv = (end > beg) ? 1.0f / (float)(end - beg) : 0.f;
    out[(long)node * 64 + lane] += (a0 + a1) * inv;
}

// ---------------- MFMA GEMMs (no LDS; frags straight from global) ----------------
// A frag (16x16x32 bf16): row = lane&15, k = (lane>>4)*8 + e  -> 16B contiguous
// B frag: col = lane&15, same k                               -> 16B contiguous in W^T
// D frag: col = lane&15, row = (lane>>4)*4 + reg

// h1b = bf16(relu(featb@Ws1 + agg1b@Wn1 + b1));  block = 4 waves x 32 rows = 128 rows
__global__ __launch_bounds__(256) void gemm1_mfma(const ushort_t* __restrict__ featb,
                                                  const ushort_t* __restrict__ agg1b,
                                                  const ushort_t* __restrict__ wT,
                                                  const float* __restrict__ b,
                                                  ushort_t* __restrict__ h1b) {
    int lane = threadIdx.x & 63;
    int w = threadIdx.x >> 6;
    int mbase = blockIdx.x * 128 + w * 32;
    int lr = lane & 15;
    int kg = (lane >> 4) * 8;

    long r0 = mbase + lr;
    long r1 = mbase + 16 + lr;
    if (r0 > N_NODES - 1) r0 = N_NODES - 1;
    if (r1 > N_NODES - 1) r1 = N_NODES - 1;

    f32x4 acc[2][8];
#pragma unroll
    for (int mt = 0; mt < 2; ++mt)
#pragma unroll
        for (int nt = 0; nt < 8; ++nt) acc[mt][nt] = (f32x4){0.f, 0.f, 0.f, 0.f};

#pragma unroll
    for (int pass = 0; pass < 2; ++pass) {
        const ushort_t* a = pass ? agg1b : featb;
        const ushort_t* wt = wT + pass * (128 * 128);
#pragma unroll
        for (int ks = 0; ks < 4; ++ks) {
            int k = ks * 32 + kg;
            bf16x8 a0 = *(const bf16x8*)(a + r0 * 128 + k);
            bf16x8 a1 = *(const bf16x8*)(a + r1 * 128 + k);
#pragma unroll
            for (int nt = 0; nt < 8; ++nt) {
                bf16x8 bb = *(const bf16x8*)(wt + (nt * 16 + lr) * 128 + k);
                acc[0][nt] = __builtin_amdgcn_mfma_f32_16x16x32_bf16(a0, bb, acc[0][nt], 0, 0, 0);
                acc[1][nt] = __builtin_amdgcn_mfma_f32_16x16x32_bf16(a1, bb, acc[1][nt], 0, 0, 0);
            }
        }
    }

    int drow = (lane >> 4) * 4;
#pragma unroll
    for (int nt = 0; nt < 8; ++nt) {
        int n = nt * 16 + lr;
        float bias = b[n];
#pragma unroll
        for (int mt = 0; mt < 2; ++mt) {
#pragma unroll
            for (int r = 0; r < 4; ++r) {
                int row = mbase + mt * 16 + drow + r;
                if (row < N_NODES) {
                    float v = fmaxf(acc[mt][nt][r] + bias, 0.f);
                    h1b[(long)row * 128 + n] = (ushort_t)f2bf(v);
                }
            }
        }
    }
}

// fused layer-2: p2b = bf16(h1b@Wn2); out = h1b@Ws2 + b2  (A-frags shared)
__global__ __launch_bounds__(256) void gemm2_mfma(const ushort_t* __restrict__ h1b,
                                                  const ushort_t* __restrict__ wT2,  // [WnT2 | WsT2]
                                                  const float* __restrict__ b2,
                                                  ushort_t* __restrict__ p2b,
                                                  float* __restrict__ out) {
    int lane = threadIdx.x & 63;
    int w = threadIdx.x >> 6;
    int mbase = blockIdx.x * 128 + w * 32;
    int lr = lane & 15;
    int kg = (lane >> 4) * 8;

    long r0 = mbase + lr;
    long r1 = mbase + 16 + lr;
    if (r0 > N_NODES - 1) r0 = N_NODES - 1;
    if (r1 > N_NODES - 1) r1 = N_NODES - 1;

    f32x4 accP[2][4], accO[2][4];
#pragma unroll
    for (int mt = 0; mt < 2; ++mt)
#pragma unroll
        for (int nt = 0; nt < 4; ++nt) {
            accP[mt][nt] = (f32x4){0.f, 0.f, 0.f, 0.f};
            accO[mt][nt] = (f32x4){0.f, 0.f, 0.f, 0.f};
        }

#pragma unroll
    for (int ks = 0; ks < 4; ++ks) {
        int k = ks * 32 + kg;
        bf16x8 a0 = *(const bf16x8*)(h1b + r0 * 128 + k);
        bf16x8 a1 = *(const bf16x8*)(h1b + r1 * 128 + k);
#pragma unroll
        for (int nt = 0; nt < 4; ++nt) {
            bf16x8 bn = *(const bf16x8*)(wT2 + (nt * 16 + lr) * 128 + k);
            bf16x8 bs = *(const bf16x8*)(wT2 + 8192 + (nt * 16 + lr) * 128 + k);
            accP[0][nt] = __builtin_amdgcn_mfma_f32_16x16x32_bf16(a0, bn, accP[0][nt], 0, 0, 0);
            accP[1][nt] = __builtin_amdgcn_mfma_f32_16x16x32_bf16(a1, bn, accP[1][nt], 0, 0, 0);
            accO[0][nt] = __builtin_amdgcn_mfma_f32_16x16x32_bf16(a0, bs, accO[0][nt], 0, 0, 0);
            accO[1][nt] = __builtin_amdgcn_mfma_f32_16x16x32_bf16(a1, bs, accO[1][nt], 0, 0, 0);
        }
    }

    int drow = (lane >> 4) * 4;
#pragma unroll
    for (int nt = 0; nt < 4; ++nt) {
        int n = nt * 16 + lr;
        float bias = b2[n];
#pragma unroll
        for (int mt = 0; mt < 2; ++mt) {
#pragma unroll
            for (int r = 0; r < 4; ++r) {
                int row = mbase + mt * 16 + drow + r;
                if (row < N_NODES) {
                    p2b[(long)row * 64 + n] = (ushort_t)f2bf(accP[mt][nt][r]);
                    out[(long)row * 64 + n] = accO[mt][nt][r] + bias;
                }
            }
        }
    }
}

extern "C" void kernel_launch(void* const* d_in, const int* in_sizes, int n_in,
                              void* d_out, int out_size, void* d_ws, size_t ws_size,
                              hipStream_t stream) {
    const float* feat = (const float*)d_in[0];
    const int* src    = (const int*)d_in[1];
    const int* dst    = (const int*)d_in[2];
    const float* Ws1  = (const float*)d_in[3];
    const float* Wn1  = (const float*)d_in[4];
    const float* b1   = (const float*)d_in[5];
    const float* Ws2  = (const float*)d_in[6];
    const float* Wn2  = (const float*)d_in[7];
    const float* b2   = (const float*)d_in[8];
    float* out = (float*)d_out;

    int* wsi      = (int*)d_ws;
    ushort_t* wsu = (ushort_t*)d_ws;
    int* cnt      = wsi + IOFF_CNT;
    int* fillpos  = wsi + IOFF_FILL;
    int* rowptr   = wsi + IOFF_ROWPTR;
    int* eidx     = wsi + IOFF_EIDX;
    int* partial  = wsi + IOFF_PART;
    ushort_t* wT    = wsu + UOFF_WT;
    ushort_t* featb = wsu + UOFF_FEATB;
    ushort_t* agg1b = wsu + UOFF_AGG1B;
    ushort_t* h1b   = wsu + UOFF_H1B;
    ushort_t* p2b   = wsu + UOFF_P2B;

    // zero cnt + fillpos (contiguous 100000 ints)
    hipMemsetAsync(wsi, 0, 100000 * sizeof(int), stream);

    // weight transpose+convert; feat -> bf16 (both independent of CSR build)
    wprep_kernel<<<(49152 + 255) / 256, 256, 0, stream>>>(Ws1, Wn1, Ws2, Wn2, wT);
    cvt_kernel<<<(N_NODES * 128 / 4 + 255) / 256, 256, 0, stream>>>(feat, featb, N_NODES * 128 / 4);

    // ---- build CSR (dst-sorted) ----
    hist_kernel<<<(N_EDGES + 255) / 256, 256, 0, stream>>>(dst, cnt);
    {
        int nblk = (N_NODES + 1023) / 1024;
        scan_part<<<nblk, 1024, 0, stream>>>(cnt, rowptr, partial);
        scan_top<<<1, 64, 0, stream>>>(partial, rowptr);
        scan_add<<<nblk, 1024, 0, stream>>>(rowptr, partial);
    }
    fill_kernel<<<(N_EDGES + 255) / 256, 256, 0, stream>>>(src, dst, rowptr, fillpos, eidx);

    // ---- layer 1 ----
    gather128_kernel<<<(N_NODES + 3) / 4, 256, 0, stream>>>(rowptr, eidx, featb, agg1b);
    gemm1_mfma<<<(N_NODES + 127) / 128, 256, 0, stream>>>(featb, agg1b, wT, b1, h1b);

    // ---- layer 2 (fused dual GEMM, aggregate-after-matmul) ----
    gemm2_mfma<<<(N_NODES + 127) / 128, 256, 0, stream>>>(h1b, wT + 32768, b2, p2b, out);
    gather64_add_kernel<<<(N_NODES + 3) / 4, 256, 0, stream>>>(rowptr, eidx, p2b, out);
}